// Round 1
// baseline (5454.397 us; speedup 1.0000x reference)
//
#include <hip/hip_runtime.h>
#include <cmath>

// ---------------------------------------------------------------------------
// RegRNN: out[b,t,:] = h_t ; h_t = tanh(xproj[b,t,:] + h_{t-1} @ Whh^T)
// xproj = seq @ Wih^T + bias   (Wih/Whh are hard-concrete gated, fp16)
//
// Phase A: MFMA fp16 GEMM writes xproj straight into d_out (in-place reuse).
// Phase B: persistent kernel, 64 WGs = 4 batch-groups x 16 j-slices.
//          Whh slice in VGPRs, h exchanged via global + agent fences.
// ---------------------------------------------------------------------------

typedef _Float16 v8h __attribute__((ext_vector_type(8)));
typedef float    v4f __attribute__((ext_vector_type(4)));

#define BB 64
#define TT 512
#define HH 1024
#define MM (BB * TT)            // 32768 rows of xproj
#define OUT_MAIN (BB * TT * HH) // 33554432
// ws layout (bytes)
#define OFF_WIH  0u
#define OFF_WHH  (2u << 20)
#define OFF_BIAS (4u << 20)
#define OFF_HBUF ((4u << 20) + 8192u)          // 2 parities * 4 groups * 16 * 1024 halves
#define OFF_CNT  ((4u << 20) + 8192u + 262144u)

__device__ __forceinline__ float hc_gate(float x) {
    float s = 1.0f / (1.0f + __expf(-x));
    float g = s * 1.2f - 0.1f;              // sigmoid*(LB-LA)+LA
    return fminf(1.0f, fmaxf(0.0f, g));
}

// ---------------- prep: gate+cast weights, bias, zero h buffers ------------
__global__ void prep_kernel(const float* __restrict__ w_ih, const float* __restrict__ w_ih_mask,
                            const float* __restrict__ w_hh, const float* __restrict__ w_hh_mask,
                            const float* __restrict__ b_ih, const float* __restrict__ b_ih_mask,
                            const float* __restrict__ b_hh, const float* __restrict__ b_hh_mask,
                            _Float16* __restrict__ Wih, _Float16* __restrict__ Whh,
                            float* __restrict__ bias, _Float16* __restrict__ hbuf,
                            int* __restrict__ cnt) {
    const int idx = blockIdx.x * 256 + threadIdx.x;   // grid 4096*256 = 1048576 exact
    Wih[idx] = (_Float16)(hc_gate(w_ih_mask[idx]) * w_ih[idx]);
    Whh[idx] = (_Float16)(hc_gate(w_hh_mask[idx]) * w_hh[idx]);
    if (idx < HH)
        bias[idx] = hc_gate(b_ih_mask[idx]) * b_ih[idx] + hc_gate(b_hh_mask[idx]) * b_hh[idx];
    if (idx < 131072) hbuf[idx] = (_Float16)0.0f;     // both parities zeroed
    if (idx < 4) cnt[idx] = 0;
}

// ---------------- Phase A: xproj GEMM --------------------------------------
// C[m,n] = sum_k seq[m,k]*Wih[n,k] + bias[n], 128x128 tile, BK=32, 256 thr.
__global__ __launch_bounds__(256, 2) void gemm_xproj(const float* __restrict__ seq,
                                                     const _Float16* __restrict__ Wih,
                                                     const float* __restrict__ bias,
                                                     float* __restrict__ out) {
    __shared__ _Float16 As[128][40];   // +8 pad: row stride 80B = 20 banks -> 2-way (free)
    __shared__ _Float16 Bs[128][40];

    const int tid  = threadIdx.x;
    const int lane = tid & 63;
    const int w    = tid >> 6;
    const int bid  = blockIdx.x;
    const int m0 = (bid >> 3) * 128;
    const int n0 = (bid & 7) * 128;
    const int mw = (w >> 1) * 64, nw = (w & 1) * 64;

    const int sr = tid >> 1;            // staging row 0..127
    const int sc = (tid & 1) * 16;      // staging col 0/16

    const float*    aSrc = seq + (m0 + sr) * HH + sc;
    const _Float16* bSrc = Wih + (n0 + sr) * HH + sc;

    const v4f vzero = {0.f, 0.f, 0.f, 0.f};
    v4f acc[4][4];
#pragma unroll
    for (int i = 0; i < 4; i++)
#pragma unroll
        for (int j = 0; j < 4; j++) acc[i][j] = vzero;

    const int arow = mw + (lane & 15);
    const int brow = nw + (lane & 15);
    const int kq   = (lane >> 4) * 8;

    for (int k0 = 0; k0 < HH; k0 += 32) {
        // stage A (fp32 -> fp16) and B
        float4 f0 = *(const float4*)(aSrc + 0);
        float4 f1 = *(const float4*)(aSrc + 4);
        float4 f2 = *(const float4*)(aSrc + 8);
        float4 f3 = *(const float4*)(aSrc + 12);
        v8h a0 = {(_Float16)f0.x, (_Float16)f0.y, (_Float16)f0.z, (_Float16)f0.w,
                  (_Float16)f1.x, (_Float16)f1.y, (_Float16)f1.z, (_Float16)f1.w};
        v8h a1 = {(_Float16)f2.x, (_Float16)f2.y, (_Float16)f2.z, (_Float16)f2.w,
                  (_Float16)f3.x, (_Float16)f3.y, (_Float16)f3.z, (_Float16)f3.w};
        v8h b0 = *(const v8h*)(bSrc + 0);
        v8h b1 = *(const v8h*)(bSrc + 8);
        *(v8h*)&As[sr][sc]     = a0;
        *(v8h*)&As[sr][sc + 8] = a1;
        *(v8h*)&Bs[sr][sc]     = b0;
        *(v8h*)&Bs[sr][sc + 8] = b1;
        __syncthreads();

        v8h af[4], bf[4];
#pragma unroll
        for (int mi = 0; mi < 4; mi++) af[mi] = *(const v8h*)&As[mi * 16 + arow][kq];
#pragma unroll
        for (int ni = 0; ni < 4; ni++) bf[ni] = *(const v8h*)&Bs[ni * 16 + brow][kq];
#pragma unroll
        for (int mi = 0; mi < 4; mi++)
#pragma unroll
            for (int ni = 0; ni < 4; ni++)
                acc[mi][ni] = __builtin_amdgcn_mfma_f32_16x16x32_f16(af[mi], bf[ni], acc[mi][ni], 0, 0, 0);
        __syncthreads();
        aSrc += 32;
        bSrc += 32;
    }

    // epilogue: D col = lane&15 (n), row = (lane>>4)*4 + reg (m)  [m89 layout]
    const int colb = lane & 15;
    const int rowq = (lane >> 4) * 4;
#pragma unroll
    for (int ni = 0; ni < 4; ni++) {
        const int col = n0 + nw + ni * 16 + colb;
        const float bz = bias[col];
#pragma unroll
        for (int mi = 0; mi < 4; mi++) {
            const int row = m0 + mw + mi * 16 + rowq;
#pragma unroll
            for (int r = 0; r < 4; r++)
                out[(row + r) * HH + col] = acc[mi][ni][r] + bz;
        }
    }
}

// ---------------- Phase B: persistent recurrence ---------------------------
// 64 WGs: g = bid>>4 (batch group of 16), jw = bid&15 (64 output cols).
// Whh rows for this wave live in 32 v8h fragments (128 VGPRs).
// Sync: per-group completion counter; agent acquire/release fences for
// cross-XCD visibility of the fp16 h slices (double-buffered by parity).
__global__ __launch_bounds__(256, 1) void rnn_steps(const _Float16* __restrict__ Whh,
                                                    float* __restrict__ out,
                                                    _Float16* __restrict__ hbuf,
                                                    int* __restrict__ cnt) {
    const int tid  = threadIdx.x;
    const int lane = tid & 63;
    const int w    = tid >> 6;
    const int bid  = blockIdx.x;
    const int g    = bid >> 4;
    const int jw   = bid & 15;

    const int jrow = jw * 64 + w * 16 + (lane & 15);  // B-operand n index == output col
    const int kq   = (lane >> 4) * 8;

    v8h Wf[32];
#pragma unroll
    for (int c = 0; c < 32; c++)
        Wf[c] = *(const v8h*)(Whh + jrow * 1024 + c * 32 + kq);

    const int bq = (lane >> 4) * 4;  // D row base = local batch index

    for (int t = 0; t < TT; t++) {
        if (tid == 0) {
            const int need = 16 * t;
            while (__hip_atomic_load(&cnt[g], __ATOMIC_RELAXED, __HIP_MEMORY_SCOPE_AGENT) < need)
                __builtin_amdgcn_s_sleep(1);
        }
        __syncthreads();
        __builtin_amdgcn_fence(__ATOMIC_ACQUIRE, "agent");  // invalidate L1/L2 before h reads

        const _Float16* hb = hbuf + (t & 1) * 65536 + g * 16384 + (lane & 15) * 1024 + kq;
        v4f a0 = {0.f, 0.f, 0.f, 0.f}, a1 = a0, a2 = a0, a3 = a0;
#pragma unroll
        for (int c = 0; c < 32; c += 4) {
            v8h h0 = *(const v8h*)(hb + (c + 0) * 32);
            v8h h1 = *(const v8h*)(hb + (c + 1) * 32);
            v8h h2 = *(const v8h*)(hb + (c + 2) * 32);
            v8h h3 = *(const v8h*)(hb + (c + 3) * 32);
            a0 = __builtin_amdgcn_mfma_f32_16x16x32_f16(h0, Wf[c + 0], a0, 0, 0, 0);
            a1 = __builtin_amdgcn_mfma_f32_16x16x32_f16(h1, Wf[c + 1], a1, 0, 0, 0);
            a2 = __builtin_amdgcn_mfma_f32_16x16x32_f16(h2, Wf[c + 2], a2, 0, 0, 0);
            a3 = __builtin_amdgcn_mfma_f32_16x16x32_f16(h3, Wf[c + 3], a3, 0, 0, 0);
        }
        v4f accv = (a0 + a1) + (a2 + a3);

        _Float16* hn = hbuf + ((t + 1) & 1) * 65536 + g * 16384;
#pragma unroll
        for (int r = 0; r < 4; r++) {
            const int bl  = bq + r;
            const int bg  = g * 16 + bl;
            const int off = (bg * TT + t) * HH + jrow;
            float pre = out[off] + accv[r];   // xproj was staged in d_out
            float hv  = tanhf(pre);
            out[off] = hv;                    // overwrite with h_t (the output)
            hn[bl * 1024 + jrow] = (_Float16)hv;
            if (t == TT - 1) out[OUT_MAIN + bg * HH + jrow] = hv;  // h_last
        }

        __syncthreads();                      // drains all waves' stores (vmcnt(0)+barrier)
        if (tid == 0) {
            __builtin_amdgcn_fence(__ATOMIC_RELEASE, "agent");  // wb L2 -> agent-visible
            __hip_atomic_fetch_add(&cnt[g], 1, __ATOMIC_RELAXED, __HIP_MEMORY_SCOPE_AGENT);
        }
    }
}

// ---------------------------------------------------------------------------
extern "C" void kernel_launch(void* const* d_in, const int* in_sizes, int n_in,
                              void* d_out, int out_size, void* d_ws, size_t ws_size,
                              hipStream_t stream) {
    const float* seq       = (const float*)d_in[0];
    const float* w_ih      = (const float*)d_in[1];
    const float* w_ih_mask = (const float*)d_in[2];
    const float* w_hh      = (const float*)d_in[3];
    const float* w_hh_mask = (const float*)d_in[4];
    const float* b_ih      = (const float*)d_in[5];
    const float* b_ih_mask = (const float*)d_in[6];
    const float* b_hh      = (const float*)d_in[7];
    const float* b_hh_mask = (const float*)d_in[8];

    float* out = (float*)d_out;
    char*  ws  = (char*)d_ws;
    _Float16* Wih  = (_Float16*)(ws + OFF_WIH);
    _Float16* Whh  = (_Float16*)(ws + OFF_WHH);
    float*    bias = (float*)(ws + OFF_BIAS);
    _Float16* hbuf = (_Float16*)(ws + OFF_HBUF);
    int*      cnt  = (int*)(ws + OFF_CNT);

    prep_kernel<<<dim3(4096), dim3(256), 0, stream>>>(w_ih, w_ih_mask, w_hh, w_hh_mask,
                                                      b_ih, b_ih_mask, b_hh, b_hh_mask,
                                                      Wih, Whh, bias, hbuf, cnt);
    gemm_xproj<<<dim3(2048), dim3(256), 0, stream>>>(seq, Wih, bias, out);
    rnn_steps<<<dim3(64), dim3(256), 0, stream>>>(Whh, out, hbuf, cnt);
}

// Round 2
// 4893.579 us; speedup vs baseline: 1.1146x; 1.1146x over previous
//
#include <hip/hip_runtime.h>
#include <cmath>

// ---------------------------------------------------------------------------
// RegRNN: out[b,t,:] = h_t ; h_t = tanh(xproj[b,t,:] + h_{t-1} @ Whh^T)
// xproj = seq @ Wih^T + bias   (Wih/Whh are hard-concrete gated, fp16)
//
// Phase A: MFMA fp16 GEMM writes xproj straight into d_out (in-place reuse).
// Phase B: persistent kernel, 64 WGs = 4 batch-groups x 16 j-slices.
//          Whh slice in VGPRs. h + counters exchanged via RELAXED AGENT-scope
//          atomics (per-access coherence at L3) -- NO cache-wide fences.
//          Ordering: __syncthreads' implicit vmcnt(0) drain before the
//          counter increment; parity double-buffer WAR-safe by counter
//          monotonicity (a WG enters step t only after all 16 group WGs
//          finished step t-1, including their reads of parity (t+1)&1).
// ---------------------------------------------------------------------------

typedef _Float16 v8h __attribute__((ext_vector_type(8)));
typedef float    v4f __attribute__((ext_vector_type(4)));
typedef unsigned long long u64;

#define BB 64
#define TT 512
#define HH 1024
#define OUT_MAIN (BB * TT * HH) // 33554432
// ws layout (bytes)
#define OFF_WIH  0u
#define OFF_WHH  (2u << 20)
#define OFF_BIAS (4u << 20)
#define OFF_HBUF ((4u << 20) + 8192u)          // 2 parities * 4 groups * 16 * 1024 halves
#define OFF_CNT  ((4u << 20) + 8192u + 262144u)

__device__ __forceinline__ float hc_gate(float x) {
    float s = 1.0f / (1.0f + __expf(-x));
    float g = s * 1.2f - 0.1f;              // sigmoid*(LB-LA)+LA
    return fminf(1.0f, fmaxf(0.0f, g));
}

__device__ __forceinline__ float fast_tanh(float x) {
    // tanh(x) = 1 - 2/(e^{2x}+1); exp->inf and ->0 both saturate correctly.
    float e = __expf(2.0f * x);
    return 1.0f - 2.0f * __builtin_amdgcn_rcpf(e + 1.0f);
}

// ---------------- prep: gate+cast weights, bias, zero h buffers ------------
__global__ void prep_kernel(const float* __restrict__ w_ih, const float* __restrict__ w_ih_mask,
                            const float* __restrict__ w_hh, const float* __restrict__ w_hh_mask,
                            const float* __restrict__ b_ih, const float* __restrict__ b_ih_mask,
                            const float* __restrict__ b_hh, const float* __restrict__ b_hh_mask,
                            _Float16* __restrict__ Wih, _Float16* __restrict__ Whh,
                            float* __restrict__ bias, _Float16* __restrict__ hbuf,
                            int* __restrict__ cnt) {
    const int idx = blockIdx.x * 256 + threadIdx.x;   // grid 4096*256 = 1048576 exact
    Wih[idx] = (_Float16)(hc_gate(w_ih_mask[idx]) * w_ih[idx]);
    Whh[idx] = (_Float16)(hc_gate(w_hh_mask[idx]) * w_hh[idx]);
    if (idx < HH)
        bias[idx] = hc_gate(b_ih_mask[idx]) * b_ih[idx] + hc_gate(b_hh_mask[idx]) * b_hh[idx];
    if (idx < 131072) hbuf[idx] = (_Float16)0.0f;     // both parities zeroed
    if (idx < 4) cnt[idx] = 0;
}

// ---------------- Phase A: xproj GEMM --------------------------------------
// C[m,n] = sum_k seq[m,k]*Wih[n,k] + bias[n], 128x128 tile, BK=32, 256 thr.
__global__ __launch_bounds__(256, 2) void gemm_xproj(const float* __restrict__ seq,
                                                     const _Float16* __restrict__ Wih,
                                                     const float* __restrict__ bias,
                                                     float* __restrict__ out) {
    __shared__ _Float16 As[128][40];   // +8 pad: row stride 80B = 20 banks -> 2-way (free)
    __shared__ _Float16 Bs[128][40];

    const int tid  = threadIdx.x;
    const int lane = tid & 63;
    const int w    = tid >> 6;
    const int bid  = blockIdx.x;
    const int m0 = (bid >> 3) * 128;
    const int n0 = (bid & 7) * 128;
    const int mw = (w >> 1) * 64, nw = (w & 1) * 64;

    const int sr = tid >> 1;            // staging row 0..127
    const int sc = (tid & 1) * 16;      // staging col 0/16

    const float*    aSrc = seq + (m0 + sr) * HH + sc;
    const _Float16* bSrc = Wih + (n0 + sr) * HH + sc;

    const v4f vzero = {0.f, 0.f, 0.f, 0.f};
    v4f acc[4][4];
#pragma unroll
    for (int i = 0; i < 4; i++)
#pragma unroll
        for (int j = 0; j < 4; j++) acc[i][j] = vzero;

    const int arow = mw + (lane & 15);
    const int brow = nw + (lane & 15);
    const int kq   = (lane >> 4) * 8;

    for (int k0 = 0; k0 < HH; k0 += 32) {
        // stage A (fp32 -> fp16) and B
        float4 f0 = *(const float4*)(aSrc + 0);
        float4 f1 = *(const float4*)(aSrc + 4);
        float4 f2 = *(const float4*)(aSrc + 8);
        float4 f3 = *(const float4*)(aSrc + 12);
        v8h a0 = {(_Float16)f0.x, (_Float16)f0.y, (_Float16)f0.z, (_Float16)f0.w,
                  (_Float16)f1.x, (_Float16)f1.y, (_Float16)f1.z, (_Float16)f1.w};
        v8h a1 = {(_Float16)f2.x, (_Float16)f2.y, (_Float16)f2.z, (_Float16)f2.w,
                  (_Float16)f3.x, (_Float16)f3.y, (_Float16)f3.z, (_Float16)f3.w};
        v8h b0 = *(const v8h*)(bSrc + 0);
        v8h b1 = *(const v8h*)(bSrc + 8);
        *(v8h*)&As[sr][sc]     = a0;
        *(v8h*)&As[sr][sc + 8] = a1;
        *(v8h*)&Bs[sr][sc]     = b0;
        *(v8h*)&Bs[sr][sc + 8] = b1;
        __syncthreads();

        v8h af[4], bf[4];
#pragma unroll
        for (int mi = 0; mi < 4; mi++) af[mi] = *(const v8h*)&As[mi * 16 + arow][kq];
#pragma unroll
        for (int ni = 0; ni < 4; ni++) bf[ni] = *(const v8h*)&Bs[ni * 16 + brow][kq];
#pragma unroll
        for (int mi = 0; mi < 4; mi++)
#pragma unroll
            for (int ni = 0; ni < 4; ni++)
                acc[mi][ni] = __builtin_amdgcn_mfma_f32_16x16x32_f16(af[mi], bf[ni], acc[mi][ni], 0, 0, 0);
        __syncthreads();
        aSrc += 32;
        bSrc += 32;
    }

    // epilogue: D col = lane&15 (n), row = (lane>>4)*4 + reg (m)  [m89 layout]
    const int colb = lane & 15;
    const int rowq = (lane >> 4) * 4;
#pragma unroll
    for (int ni = 0; ni < 4; ni++) {
        const int col = n0 + nw + ni * 16 + colb;
        const float bz = bias[col];
#pragma unroll
        for (int mi = 0; mi < 4; mi++) {
            const int row = m0 + mw + mi * 16 + rowq;
#pragma unroll
            for (int r = 0; r < 4; r++)
                out[(row + r) * HH + col] = acc[mi][ni][r] + bz;
        }
    }
}

// ---------------- Phase B: persistent recurrence ---------------------------
// 64 WGs: g = bid>>4 (batch group of 16), jw = bid&15 (64 output cols).
// Whh rows for this wave live in 32 v8h fragments (128 VGPRs).
__global__ __launch_bounds__(256, 1) void rnn_steps(const _Float16* __restrict__ Whh,
                                                    float* __restrict__ out,
                                                    _Float16* __restrict__ hbuf,
                                                    int* __restrict__ cnt) {
    __shared__ _Float16 tile[16][64];   // h transpose staging (2 KB)

    const int tid  = threadIdx.x;
    const int lane = tid & 63;
    const int w    = tid >> 6;
    const int bid  = blockIdx.x;
    const int g    = bid >> 4;
    const int jw   = bid & 15;

    const int jrow = jw * 64 + w * 16 + (lane & 15);  // B-operand n index == output col
    const int kq   = (lane >> 4) * 8;

    v8h Wf[32];
#pragma unroll
    for (int c = 0; c < 32; c++)
        Wf[c] = *(const v8h*)(Whh + jrow * 1024 + c * 32 + kq);

    const int bq = (lane >> 4) * 4;      // D row base = local batch index
    const int cl = w * 16 + (lane & 15); // local col for LDS transpose write
    const int tb = tid >> 4;             // transpose: batch this thread stores
    const int tc = (tid & 15) * 4;       // transpose: col chunk (4 halves = 8B)

    // xproj prefetch for t=0 (gemm output staged in d_out)
    float xp[4];
#pragma unroll
    for (int r = 0; r < 4; r++)
        xp[r] = out[((g * 16 + bq + r) * TT + 0) * HH + jrow];

    for (int t = 0; t < TT; t++) {
        if (tid == 0) {
            const int need = 16 * t;
            while (__hip_atomic_load(&cnt[g], __ATOMIC_RELAXED, __HIP_MEMORY_SCOPE_AGENT) < need)
                __builtin_amdgcn_s_sleep(1);
        }
        __syncthreads();   // A: release all waves into step t

        // h_{t-1} loads: agent-scope relaxed 8B atomics (coherent at L3)
        const _Float16* hb = hbuf + (t & 1) * 65536 + g * 16384 + (lane & 15) * 1024 + kq;
        v4f a0 = {0.f, 0.f, 0.f, 0.f}, a1 = a0, a2 = a0, a3 = a0;
#pragma unroll
        for (int c = 0; c < 32; c += 4) {
            union { v8h v; u64 u[2]; } h0, h1, h2, h3;
            const u64* p0 = (const u64*)(hb + (c + 0) * 32);
            const u64* p1 = (const u64*)(hb + (c + 1) * 32);
            const u64* p2 = (const u64*)(hb + (c + 2) * 32);
            const u64* p3 = (const u64*)(hb + (c + 3) * 32);
            h0.u[0] = __hip_atomic_load(p0,     __ATOMIC_RELAXED, __HIP_MEMORY_SCOPE_AGENT);
            h0.u[1] = __hip_atomic_load(p0 + 1, __ATOMIC_RELAXED, __HIP_MEMORY_SCOPE_AGENT);
            h1.u[0] = __hip_atomic_load(p1,     __ATOMIC_RELAXED, __HIP_MEMORY_SCOPE_AGENT);
            h1.u[1] = __hip_atomic_load(p1 + 1, __ATOMIC_RELAXED, __HIP_MEMORY_SCOPE_AGENT);
            h2.u[0] = __hip_atomic_load(p2,     __ATOMIC_RELAXED, __HIP_MEMORY_SCOPE_AGENT);
            h2.u[1] = __hip_atomic_load(p2 + 1, __ATOMIC_RELAXED, __HIP_MEMORY_SCOPE_AGENT);
            h3.u[0] = __hip_atomic_load(p3,     __ATOMIC_RELAXED, __HIP_MEMORY_SCOPE_AGENT);
            h3.u[1] = __hip_atomic_load(p3 + 1, __ATOMIC_RELAXED, __HIP_MEMORY_SCOPE_AGENT);
            a0 = __builtin_amdgcn_mfma_f32_16x16x32_f16(h0.v, Wf[c + 0], a0, 0, 0, 0);
            a1 = __builtin_amdgcn_mfma_f32_16x16x32_f16(h1.v, Wf[c + 1], a1, 0, 0, 0);
            a2 = __builtin_amdgcn_mfma_f32_16x16x32_f16(h2.v, Wf[c + 2], a2, 0, 0, 0);
            a3 = __builtin_amdgcn_mfma_f32_16x16x32_f16(h3.v, Wf[c + 3], a3, 0, 0, 0);
        }
        v4f accv = (a0 + a1) + (a2 + a3);

        float hv4[4];
#pragma unroll
        for (int r = 0; r < 4; r++) {
            hv4[r] = fast_tanh(xp[r] + accv[r]);
            tile[bq + r][cl] = (_Float16)hv4[r];
        }
        __syncthreads();   // B: transpose tile complete

        // one 8B agent store per thread: hbuf[(t+1)&1][g][tb][jw*64+tc .. +3]
        {
            u64 val = *(const u64*)&tile[tb][tc];
            u64* dst = (u64*)(hbuf + ((t + 1) & 1) * 65536 + g * 16384 + tb * 1024 + jw * 64 + tc);
            __hip_atomic_store(dst, val, __ATOMIC_RELAXED, __HIP_MEMORY_SCOPE_AGENT);
        }
        __syncthreads();   // C: implicit vmcnt(0) -> all waves' h-stores drained

        if (tid == 0)
            __hip_atomic_fetch_add(&cnt[g], 1, __ATOMIC_RELAXED, __HIP_MEMORY_SCOPE_AGENT);

        // off critical path: fp32 outputs + next xproj prefetch (hide under poll)
#pragma unroll
        for (int r = 0; r < 4; r++) {
            const int bg  = g * 16 + bq + r;
            out[(bg * TT + t) * HH + jrow] = hv4[r];
            if (t == TT - 1) out[OUT_MAIN + bg * HH + jrow] = hv4[r];
        }
        if (t + 1 < TT) {
#pragma unroll
            for (int r = 0; r < 4; r++)
                xp[r] = out[((g * 16 + bq + r) * TT + (t + 1)) * HH + jrow];
        }
    }
}

// ---------------------------------------------------------------------------
extern "C" void kernel_launch(void* const* d_in, const int* in_sizes, int n_in,
                              void* d_out, int out_size, void* d_ws, size_t ws_size,
                              hipStream_t stream) {
    const float* seq       = (const float*)d_in[0];
    const float* w_ih      = (const float*)d_in[1];
    const float* w_ih_mask = (const float*)d_in[2];
    const float* w_hh      = (const float*)d_in[3];
    const float* w_hh_mask = (const float*)d_in[4];
    const float* b_ih      = (const float*)d_in[5];
    const float* b_ih_mask = (const float*)d_in[6];
    const float* b_hh      = (const float*)d_in[7];
    const float* b_hh_mask = (const float*)d_in[8];

    float* out = (float*)d_out;
    char*  ws  = (char*)d_ws;
    _Float16* Wih  = (_Float16*)(ws + OFF_WIH);
    _Float16* Whh  = (_Float16*)(ws + OFF_WHH);
    float*    bias = (float*)(ws + OFF_BIAS);
    _Float16* hbuf = (_Float16*)(ws + OFF_HBUF);
    int*      cnt  = (int*)(ws + OFF_CNT);

    prep_kernel<<<dim3(4096), dim3(256), 0, stream>>>(w_ih, w_ih_mask, w_hh, w_hh_mask,
                                                      b_ih, b_ih_mask, b_hh, b_hh_mask,
                                                      Wih, Whh, bias, hbuf, cnt);
    gemm_xproj<<<dim3(2048), dim3(256), 0, stream>>>(seq, Wih, bias, out);
    rnn_steps<<<dim3(64), dim3(256), 0, stream>>>(Whh, out, hbuf, cnt);
}